// Round 1
// baseline (1744.116 us; speedup 1.0000x reference)
//
#include <hip/hip_runtime.h>

// ---------------- CSR construction ----------------

__global__ void count_kernel(const int* __restrict__ dst, int* __restrict__ counts, int E) {
    int e = blockIdx.x * 256 + threadIdx.x;
    if (e < E) atomicAdd(&counts[dst[e]], 1);
}

__global__ void dinv_kernel(const int* __restrict__ counts, float* __restrict__ dinv, int N) {
    int v = blockIdx.x * 256 + threadIdx.x;
    if (v < N) dinv[v] = rsqrtf((float)counts[v] + 1.0f);
}

// Per-block exclusive scan of counts -> rowptr (partial), block sums -> bsums
__global__ void scan_local(const int* __restrict__ counts, int* __restrict__ rowptr,
                           int* __restrict__ bsums, int N) {
    __shared__ int sm[256];
    int t = threadIdx.x;
    int gid = blockIdx.x * 256 + t;
    int v = (gid < N) ? counts[gid] : 0;
    int x = v;
    sm[t] = x; __syncthreads();
    for (int off = 1; off < 256; off <<= 1) {
        int y = (t >= off) ? sm[t - off] : 0;
        __syncthreads();
        x += y; sm[t] = x; __syncthreads();
    }
    if (gid < N) rowptr[gid] = x - v;          // exclusive within block
    if (t == 255) bsums[blockIdx.x] = x;       // inclusive block total
}

// Single-block exclusive scan of block sums (nb <= 512)
__global__ void scan_bsums(int* bsums, int nb) {
    __shared__ int sm[512];
    int t = threadIdx.x;
    int v = (t < nb) ? bsums[t] : 0;
    int x = v;
    sm[t] = x; __syncthreads();
    for (int off = 1; off < 512; off <<= 1) {
        int y = (t >= off) ? sm[t - off] : 0;
        __syncthreads();
        x += y; sm[t] = x; __syncthreads();
    }
    if (t < nb) bsums[t] = x - v;
}

__global__ void scan_add(int* __restrict__ rowptr, const int* __restrict__ bsums, int N) {
    int gid = blockIdx.x * 256 + threadIdx.x;
    if (gid < N) rowptr[gid] += bsums[blockIdx.x];
}

__global__ void fill_kernel(const int* __restrict__ src, const int* __restrict__ dst,
                            const int* __restrict__ rowptr, int* __restrict__ fillc,
                            int* __restrict__ csr, int E) {
    int e = blockIdx.x * 256 + threadIdx.x;
    if (e < E) {
        int d = dst[e];
        int pos = rowptr[d] + atomicAdd(&fillc[d], 1);
        csr[pos] = src[e];
    }
}

// ---------------- xw = X @ W  (64x64 weight in LDS, 4 rows/wave) ----------------

__global__ void gemm64_kernel(const float* __restrict__ X, const float* __restrict__ W,
                              float* __restrict__ out, int N) {
    __shared__ float Wl[64 * 64];
    int tid = threadIdx.x;
    for (int i = tid; i < 4096; i += 256) Wl[i] = W[i];
    __syncthreads();
    int lane = tid & 63, wave = tid >> 6;
    int w0 = blockIdx.x * 4 + wave;
    int nw = gridDim.x * 4;
    for (int r4 = w0 * 4; r4 < N; r4 += nw * 4) {
        float x0 = (r4 + 0 < N) ? X[(size_t)(r4 + 0) * 64 + lane] : 0.f;
        float x1 = (r4 + 1 < N) ? X[(size_t)(r4 + 1) * 64 + lane] : 0.f;
        float x2 = (r4 + 2 < N) ? X[(size_t)(r4 + 2) * 64 + lane] : 0.f;
        float x3 = (r4 + 3 < N) ? X[(size_t)(r4 + 3) * 64 + lane] : 0.f;
        float a0 = 0.f, a1 = 0.f, a2 = 0.f, a3 = 0.f;
#pragma unroll
        for (int k = 0; k < 64; ++k) {
            float w = Wl[k * 64 + lane];
            a0 = fmaf(__shfl(x0, k), w, a0);
            a1 = fmaf(__shfl(x1, k), w, a1);
            a2 = fmaf(__shfl(x2, k), w, a2);
            a3 = fmaf(__shfl(x3, k), w, a3);
        }
        if (r4 + 0 < N) out[(size_t)(r4 + 0) * 64 + lane] = a0;
        if (r4 + 1 < N) out[(size_t)(r4 + 1) * 64 + lane] = a1;
        if (r4 + 2 < N) out[(size_t)(r4 + 2) * 64 + lane] = a2;
        if (r4 + 3 < N) out[(size_t)(r4 + 3) * 64 + lane] = a3;
    }
}

// ---------------- aggregation: h[v] = relu(dv*(sum dinv[s]*xw[s]) + dv^2*xw[v] + b) ----------------

__global__ void agg_kernel(const float* __restrict__ XW, const int* __restrict__ csr,
                           const int* __restrict__ rowptr, const int* __restrict__ counts,
                           const float* __restrict__ dinv, const float* __restrict__ bias,
                           float* __restrict__ out, int N) {
    int tid = threadIdx.x;
    int lane = tid & 63, wave = tid >> 6;
    int v = blockIdx.x * 4 + wave;
    if (v >= N) return;
    int start = rowptr[v];
    int cnt = counts[v];
    float dv = dinv[v];
    float acc = dv * XW[(size_t)v * 64 + lane];     // self-loop (gets another *dv at the end)
    for (int base = 0; base < cnt; base += 64) {
        int nb = min(64, cnt - base);
        int idx = 0; float ds = 0.f;
        if (lane < nb) {
            idx = csr[start + base + lane];
            ds = dinv[idx];
        }
        for (int j = 0; j < nb; ++j) {
            int s = __shfl(idx, j);
            float d = __shfl(ds, j);
            acc = fmaf(d, XW[(size_t)s * 64 + lane], acc);
        }
    }
    float r = fmaf(dv, acc, bias[lane]);
    out[(size_t)v * 64 + lane] = fmaxf(r, 0.f);
}

// ---------------- head: out = relu(h@dW1+db1) @ dW2 + db2 ----------------

__global__ void dense_kernel(const float* __restrict__ H, const float* __restrict__ dW1,
                             const float* __restrict__ db1, const float* __restrict__ dW2,
                             const float* __restrict__ db2, float* __restrict__ out, int N) {
    __shared__ float D1[64 * 64];
    int tid = threadIdx.x;
    for (int i = tid; i < 4096; i += 256) D1[i] = dW1[i];
    __syncthreads();
    int lane = tid & 63, wave = tid >> 6;
    int j = lane & 15, part = lane >> 4;
    float d2r[16];
#pragma unroll
    for (int kk = 0; kk < 16; ++kk) d2r[kk] = dW2[(part * 16 + kk) * 16 + j];
    float bb1 = db1[lane];
    float bb2 = db2[j];
    int w0 = blockIdx.x * 4 + wave;
    int nw = gridDim.x * 4;
    for (int r = w0; r < N; r += nw) {
        float h0 = H[(size_t)r * 64 + lane];
        float acc = bb1;
#pragma unroll
        for (int k = 0; k < 64; ++k)
            acc = fmaf(__shfl(h0, k), D1[k * 64 + lane], acc);
        acc = fmaxf(acc, 0.f);
        float o = 0.f;
#pragma unroll
        for (int kk = 0; kk < 16; ++kk)
            o = fmaf(__shfl(acc, part * 16 + kk), d2r[kk], o);
        o += __shfl_xor(o, 16);
        o += __shfl_xor(o, 32);
        if (lane < 16) out[(size_t)r * 16 + lane] = o + bb2;
    }
}

// ---------------- launch ----------------

extern "C" void kernel_launch(void* const* d_in, const int* in_sizes, int n_in,
                              void* d_out, int out_size, void* d_ws, size_t ws_size,
                              hipStream_t stream) {
    const float* x   = (const float*)d_in[0];
    const int*   ei  = (const int*)d_in[1];
    const float* W1  = (const float*)d_in[2];
    const float* b1  = (const float*)d_in[3];
    const float* W2  = (const float*)d_in[4];
    const float* b2  = (const float*)d_in[5];
    const float* dW1 = (const float*)d_in[6];
    const float* db1 = (const float*)d_in[7];
    const float* dW2 = (const float*)d_in[8];
    const float* db2 = (const float*)d_in[9];
    float* out = (float*)d_out;

    int N = in_sizes[0] / 64;
    int E = in_sizes[1] / 2;
    const int* src = ei;
    const int* dst = ei + E;

    size_t off = 0;
    auto alloc = [&](size_t bytes) {
        void* p = (char*)d_ws + off;
        off += (bytes + 511) & ~(size_t)511;
        return p;
    };
    int*   counts = (int*)alloc((size_t)N * 4);
    int*   fillc  = (int*)alloc((size_t)N * 4);
    int*   rowptr = (int*)alloc((size_t)N * 4);
    int*   bsums  = (int*)alloc(512 * 4);
    int*   csr    = (int*)alloc((size_t)E * 4);
    float* dinv   = (float*)alloc((size_t)N * 4);
    float* xw     = (float*)alloc((size_t)N * 64 * 4);
    float* h      = (float*)alloc((size_t)N * 64 * 4);

    hipMemsetAsync(counts, 0, (size_t)N * 4, stream);
    hipMemsetAsync(fillc, 0, (size_t)N * 4, stream);

    int nbN = (N + 255) / 256;      // 391 blocks for N=100000 (fits scan_bsums<=512)
    int nbE = (E + 255) / 256;

    count_kernel<<<nbE, 256, 0, stream>>>(dst, counts, E);
    dinv_kernel<<<nbN, 256, 0, stream>>>(counts, dinv, N);
    scan_local<<<nbN, 256, 0, stream>>>(counts, rowptr, bsums, N);
    scan_bsums<<<1, 512, 0, stream>>>(bsums, nbN);
    scan_add<<<nbN, 256, 0, stream>>>(rowptr, bsums, N);
    fill_kernel<<<nbE, 256, 0, stream>>>(src, dst, rowptr, fillc, csr, E);

    // layer 1
    gemm64_kernel<<<1024, 256, 0, stream>>>(x, W1, xw, N);
    agg_kernel<<<(N + 3) / 4, 256, 0, stream>>>(xw, csr, rowptr, counts, dinv, b1, h, N);
    // layer 2
    gemm64_kernel<<<1024, 256, 0, stream>>>(h, W2, xw, N);
    agg_kernel<<<(N + 3) / 4, 256, 0, stream>>>(xw, csr, rowptr, counts, dinv, b2, h, N);
    // MLP head
    dense_kernel<<<2048, 256, 0, stream>>>(h, dW1, db1, dW2, db2, out, N);
}

// Round 2
// 1249.246 us; speedup vs baseline: 1.3961x; 1.3961x over previous
//
#include <hip/hip_runtime.h>

// ---------------- CSR construction ----------------

__global__ void count_kernel(const int* __restrict__ dst, int* __restrict__ counts, int E) {
    int e = blockIdx.x * 256 + threadIdx.x;
    if (e < E) atomicAdd(&counts[dst[e]], 1);
}

// Per-block exclusive scan of counts -> rowptr (partial), block sums -> bsums.
// Also emits dinv[v] = rsqrt(deg+1) (fused; counts already in registers).
__global__ void scan_local(const int* __restrict__ counts, int* __restrict__ rowptr,
                           int* __restrict__ bsums, float* __restrict__ dinv, int N) {
    __shared__ int sm[256];
    int t = threadIdx.x;
    int gid = blockIdx.x * 256 + t;
    int v = (gid < N) ? counts[gid] : 0;
    if (gid < N) dinv[gid] = rsqrtf((float)v + 1.0f);
    int x = v;
    sm[t] = x; __syncthreads();
    for (int off = 1; off < 256; off <<= 1) {
        int y = (t >= off) ? sm[t - off] : 0;
        __syncthreads();
        x += y; sm[t] = x; __syncthreads();
    }
    if (gid < N) rowptr[gid] = x - v;          // exclusive within block
    if (t == 255) bsums[blockIdx.x] = x;       // inclusive block total
}

// Single-block exclusive scan of block sums (nb <= 512)
__global__ void scan_bsums(int* bsums, int nb) {
    __shared__ int sm[512];
    int t = threadIdx.x;
    int v = (t < nb) ? bsums[t] : 0;
    int x = v;
    sm[t] = x; __syncthreads();
    for (int off = 1; off < 512; off <<= 1) {
        int y = (t >= off) ? sm[t - off] : 0;
        __syncthreads();
        x += y; sm[t] = x; __syncthreads();
    }
    if (t < nb) bsums[t] = x - v;
}

__global__ void scan_add(int* __restrict__ rowptr, const int* __restrict__ bsums, int N) {
    int gid = blockIdx.x * 256 + threadIdx.x;
    if (gid < N) rowptr[gid] += bsums[blockIdx.x];
}

__global__ void fill_kernel(const int* __restrict__ src, const int* __restrict__ dst,
                            const int* __restrict__ rowptr, int* __restrict__ fillc,
                            int* __restrict__ csr, int E) {
    int e = blockIdx.x * 256 + threadIdx.x;
    if (e < E) {
        int d = dst[e];
        int pos = rowptr[d] + atomicAdd(&fillc[d], 1);
        csr[pos] = src[e];
    }
}

// ---------------- xw = X @ W  (CONTROL: unchanged from round 1) ----------------

__global__ void gemm64_kernel(const float* __restrict__ X, const float* __restrict__ W,
                              float* __restrict__ out, int N) {
    __shared__ float Wl[64 * 64];
    int tid = threadIdx.x;
    for (int i = tid; i < 4096; i += 256) Wl[i] = W[i];
    __syncthreads();
    int lane = tid & 63, wave = tid >> 6;
    int w0 = blockIdx.x * 4 + wave;
    int nw = gridDim.x * 4;
    for (int r4 = w0 * 4; r4 < N; r4 += nw * 4) {
        float x0 = (r4 + 0 < N) ? X[(size_t)(r4 + 0) * 64 + lane] : 0.f;
        float x1 = (r4 + 1 < N) ? X[(size_t)(r4 + 1) * 64 + lane] : 0.f;
        float x2 = (r4 + 2 < N) ? X[(size_t)(r4 + 2) * 64 + lane] : 0.f;
        float x3 = (r4 + 3 < N) ? X[(size_t)(r4 + 3) * 64 + lane] : 0.f;
        float a0 = 0.f, a1 = 0.f, a2 = 0.f, a3 = 0.f;
#pragma unroll
        for (int k = 0; k < 64; ++k) {
            float w = Wl[k * 64 + lane];
            a0 = fmaf(__shfl(x0, k), w, a0);
            a1 = fmaf(__shfl(x1, k), w, a1);
            a2 = fmaf(__shfl(x2, k), w, a2);
            a3 = fmaf(__shfl(x3, k), w, a3);
        }
        if (r4 + 0 < N) out[(size_t)(r4 + 0) * 64 + lane] = a0;
        if (r4 + 1 < N) out[(size_t)(r4 + 1) * 64 + lane] = a1;
        if (r4 + 2 < N) out[(size_t)(r4 + 2) * 64 + lane] = a2;
        if (r4 + 3 < N) out[(size_t)(r4 + 3) * 64 + lane] = a3;
    }
}

// ---------------- layer1 agg fused with @W2:  Y = relu(agg(XW)+b1) @ W2 ----------------

__global__ void agg_mm_kernel(const float* __restrict__ XW, const int* __restrict__ csr,
                              const int* __restrict__ rowptr, const int* __restrict__ counts,
                              const float* __restrict__ dinv, const float* __restrict__ bias,
                              const float* __restrict__ W2, float* __restrict__ Y, int N) {
    __shared__ float Wl[64 * 64];
    int tid = threadIdx.x;
    for (int i = tid; i < 4096; i += 256) Wl[i] = W2[i];
    __syncthreads();
    int lane = tid & 63, wave = tid >> 6;
    float bb = bias[lane];
    int v0 = blockIdx.x * 4 + wave;
    int stride = gridDim.x * 4;
    for (int v = v0; v < N; v += stride) {
        int start = rowptr[v], cnt = counts[v];
        float dv = dinv[v];
        float acc = dv * XW[(size_t)v * 64 + lane];
        for (int base = 0; base < cnt; base += 64) {
            int nb = min(64, cnt - base);
            int idx = 0; float ds = 0.f;
            if (lane < nb) { idx = csr[start + base + lane]; ds = dinv[idx]; }
            for (int j = 0; j < nb; ++j) {
                int s = __shfl(idx, j);
                float d = __shfl(ds, j);
                acc = fmaf(d, XW[(size_t)s * 64 + lane], acc);
            }
        }
        float h = fmaxf(fmaf(dv, acc, bb), 0.f);
        float y = 0.f;
#pragma unroll
        for (int k = 0; k < 64; ++k)
            y = fmaf(__shfl(h, k), Wl[k * 64 + lane], y);
        Y[(size_t)v * 64 + lane] = y;
    }
}

// ------- layer2 agg fused with MLP head:  out = relu(relu(agg(Y)+b2)@dW1+db1)@dW2+db2 -------

__global__ void agg_head_kernel(const float* __restrict__ Y, const int* __restrict__ csr,
                                const int* __restrict__ rowptr, const int* __restrict__ counts,
                                const float* __restrict__ dinv, const float* __restrict__ b2,
                                const float* __restrict__ dW1, const float* __restrict__ db1,
                                const float* __restrict__ dW2, const float* __restrict__ db2,
                                float* __restrict__ out, int N) {
    __shared__ float D1[64 * 64];
    int tid = threadIdx.x;
    for (int i = tid; i < 4096; i += 256) D1[i] = dW1[i];
    __syncthreads();
    int lane = tid & 63, wave = tid >> 6;
    int j = lane & 15, part = lane >> 4;
    float d2r[16];
#pragma unroll
    for (int kk = 0; kk < 16; ++kk) d2r[kk] = dW2[(part * 16 + kk) * 16 + j];
    float bbl = b2[lane];
    float bb1 = db1[lane];
    float ob  = db2[j];
    int v0 = blockIdx.x * 4 + wave;
    int stride = gridDim.x * 4;
    for (int v = v0; v < N; v += stride) {
        int start = rowptr[v], cnt = counts[v];
        float dv = dinv[v];
        float acc = dv * Y[(size_t)v * 64 + lane];
        for (int base = 0; base < cnt; base += 64) {
            int nb = min(64, cnt - base);
            int idx = 0; float ds = 0.f;
            if (lane < nb) { idx = csr[start + base + lane]; ds = dinv[idx]; }
            for (int jj = 0; jj < nb; ++jj) {
                int s = __shfl(idx, jj);
                float d = __shfl(ds, jj);
                acc = fmaf(d, Y[(size_t)s * 64 + lane], acc);
            }
        }
        float h2 = fmaxf(fmaf(dv, acc, bbl), 0.f);
        float a1 = bb1;
#pragma unroll
        for (int k = 0; k < 64; ++k)
            a1 = fmaf(__shfl(h2, k), D1[k * 64 + lane], a1);
        a1 = fmaxf(a1, 0.f);
        float o = 0.f;
#pragma unroll
        for (int kk = 0; kk < 16; ++kk)
            o = fmaf(__shfl(a1, part * 16 + kk), d2r[kk], o);
        o += __shfl_xor(o, 16);
        o += __shfl_xor(o, 32);
        if (lane < 16) out[(size_t)v * 16 + lane] = o + ob;
    }
}

// ---------------- launch ----------------

extern "C" void kernel_launch(void* const* d_in, const int* in_sizes, int n_in,
                              void* d_out, int out_size, void* d_ws, size_t ws_size,
                              hipStream_t stream) {
    const float* x   = (const float*)d_in[0];
    const int*   ei  = (const int*)d_in[1];
    const float* W1  = (const float*)d_in[2];
    const float* b1  = (const float*)d_in[3];
    const float* W2  = (const float*)d_in[4];
    const float* b2  = (const float*)d_in[5];
    const float* dW1 = (const float*)d_in[6];
    const float* db1 = (const float*)d_in[7];
    const float* dW2 = (const float*)d_in[8];
    const float* db2 = (const float*)d_in[9];
    float* out = (float*)d_out;

    int N = in_sizes[0] / 64;
    int E = in_sizes[1] / 2;
    const int* src = ei;
    const int* dst = ei + E;

    size_t off = 0;
    auto alloc = [&](size_t bytes) {
        void* p = (char*)d_ws + off;
        off += (bytes + 511) & ~(size_t)511;
        return p;
    };
    int*   counts = (int*)alloc((size_t)N * 4);
    int*   fillc  = (int*)alloc((size_t)N * 4);
    int*   rowptr = (int*)alloc((size_t)N * 4);
    int*   bsums  = (int*)alloc(512 * 4);
    int*   csr    = (int*)alloc((size_t)E * 4);
    float* dinv   = (float*)alloc((size_t)N * 4);
    float* xw     = (float*)alloc((size_t)N * 64 * 4);
    float* yw     = (float*)alloc((size_t)N * 64 * 4);

    hipMemsetAsync(counts, 0, (size_t)N * 4, stream);
    hipMemsetAsync(fillc, 0, (size_t)N * 4, stream);

    int nbN = (N + 255) / 256;      // 391 blocks (fits scan_bsums<=512)
    int nbE = (E + 255) / 256;

    count_kernel<<<nbE, 256, 0, stream>>>(dst, counts, E);
    scan_local<<<nbN, 256, 0, stream>>>(counts, rowptr, bsums, dinv, N);
    scan_bsums<<<1, 512, 0, stream>>>(bsums, nbN);
    scan_add<<<nbN, 256, 0, stream>>>(rowptr, bsums, N);
    fill_kernel<<<nbE, 256, 0, stream>>>(src, dst, rowptr, fillc, csr, E);

    // layer 1 gemm (CONTROL: unchanged)
    gemm64_kernel<<<1024, 256, 0, stream>>>(x, W1, xw, N);
    // layer 1 aggregation fused with layer 2 gemm
    agg_mm_kernel<<<2048, 256, 0, stream>>>(xw, csr, rowptr, counts, dinv, b1, W2, yw, N);
    // layer 2 aggregation fused with MLP head
    agg_head_kernel<<<2048, 256, 0, stream>>>(yw, csr, rowptr, counts, dinv, b2,
                                              dW1, db1, dW2, db2, out, N);
}

// Round 3
// 1099.134 us; speedup vs baseline: 1.5868x; 1.1366x over previous
//
#include <hip/hip_runtime.h>

// ---------------- CSR construction ----------------

__global__ void count_kernel(const int* __restrict__ dst, int* __restrict__ counts, int E) {
    int e = blockIdx.x * 256 + threadIdx.x;
    if (e < E) atomicAdd(&counts[dst[e]], 1);
}

// Per-block exclusive scan of counts -> rowptr (partial), block sums -> bsums.
// Also emits dinv[v] = rsqrt(deg+1).
__global__ void scan_local(const int* __restrict__ counts, int* __restrict__ rowptr,
                           int* __restrict__ bsums, float* __restrict__ dinv, int N) {
    __shared__ int sm[256];
    int t = threadIdx.x;
    int gid = blockIdx.x * 256 + t;
    int v = (gid < N) ? counts[gid] : 0;
    if (gid < N) dinv[gid] = rsqrtf((float)v + 1.0f);
    int x = v;
    sm[t] = x; __syncthreads();
    for (int off = 1; off < 256; off <<= 1) {
        int y = (t >= off) ? sm[t - off] : 0;
        __syncthreads();
        x += y; sm[t] = x; __syncthreads();
    }
    if (gid < N) rowptr[gid] = x - v;
    if (t == 255) bsums[blockIdx.x] = x;
}

__global__ void scan_bsums(int* bsums, int nb) {
    __shared__ int sm[512];
    int t = threadIdx.x;
    int v = (t < nb) ? bsums[t] : 0;
    int x = v;
    sm[t] = x; __syncthreads();
    for (int off = 1; off < 512; off <<= 1) {
        int y = (t >= off) ? sm[t - off] : 0;
        __syncthreads();
        x += y; sm[t] = x; __syncthreads();
    }
    if (t < nb) bsums[t] = x - v;
}

__global__ void scan_add(int* __restrict__ rowptr, const int* __restrict__ bsums, int N) {
    int gid = blockIdx.x * 256 + threadIdx.x;
    if (gid < N) rowptr[gid] += bsums[blockIdx.x];
}

// fill CSR; also precompute per-edge weight csrw = dinv[src] so the agg inner
// loop has no dependent scalar-load chain.
__global__ void fill_kernel(const int* __restrict__ src, const int* __restrict__ dst,
                            const int* __restrict__ rowptr, int* __restrict__ fillc,
                            const float* __restrict__ dinv,
                            int* __restrict__ csr, float* __restrict__ csrw, int E) {
    int e = blockIdx.x * 256 + threadIdx.x;
    if (e < E) {
        int d = dst[e];
        int s = src[e];
        int pos = rowptr[d] + atomicAdd(&fillc[d], 1);
        csr[pos] = s;
        csrw[pos] = dinv[s];
    }
}

// ---------------- xw = X @ W : lane = out column, x-row via scalar loads ----------------

__global__ void gemm64_kernel(const float* __restrict__ X, const float* __restrict__ W,
                              float* __restrict__ out, int N) {
    int tid = threadIdx.x;
    int lane = tid & 63;
    int wi = __builtin_amdgcn_readfirstlane(tid >> 6);  // wave-uniform wave id
    // W column for this lane, registers, loaded once (coalesced per k)
    float wc[64];
#pragma unroll
    for (int k = 0; k < 64; ++k) wc[k] = W[k * 64 + lane];
    int r0 = blockIdx.x * 4 + wi;
    int nw = gridDim.x * 4;
    for (int r = r0; r < N; r += nw) {
        const float* xr = X + (size_t)r * 64;   // uniform address -> s_load batches
        float a0 = 0.f, a1 = 0.f;
#pragma unroll
        for (int k = 0; k < 64; k += 2) {
            a0 = fmaf(xr[k],     wc[k],     a0);
            a1 = fmaf(xr[k + 1], wc[k + 1], a1);
        }
        out[(size_t)r * 64 + lane] = a0 + a1;
    }
}

// ---------------- layer1 agg fused with @W2:  Y = relu(agg(XW)+b1) @ W2 ----------------

__global__ void agg_mm_kernel(const float* __restrict__ XW, const int* __restrict__ csr,
                              const float* __restrict__ csrw,
                              const int* __restrict__ rowptr, const int* __restrict__ counts,
                              const float* __restrict__ dinv, const float* __restrict__ bias,
                              const float* __restrict__ W2, float* __restrict__ Y, int N) {
    __shared__ float hbuf[4][256];      // per-wave transpose scratch (wave-private)
    int tid = threadIdx.x;
    int lane = tid & 63;
    int wi = __builtin_amdgcn_readfirstlane(tid >> 6);
    float wc[64];                       // W2 column for this lane
#pragma unroll
    for (int k = 0; k < 64; ++k) wc[k] = W2[k * 64 + lane];
    float bb = bias[lane];
    float* hb = &hbuf[wi][0];
    int g0 = blockIdx.x * 4 + wi;
    int ng = gridDim.x * 4;
    int NG = (N + 3) >> 2;
    for (int g = g0; g < NG; g += ng) {
        int v0 = g * 4;
        float h[4];
#pragma unroll
        for (int rr = 0; rr < 4; ++rr) {
            int v = v0 + rr;
            float hv = 0.f;
            if (v < N) {
                int start = rowptr[v];      // uniform -> s_load
                int cnt = counts[v];
                float dv = dinv[v];
                float acc = dv * XW[(size_t)v * 64 + lane];
                int j = 0;
                for (; j + 8 <= cnt; j += 8) {
                    const int*   cp = csr  + start + j;   // uniform -> s_load_dwordx8
                    const float* wp = csrw + start + j;
                    int   s0 = cp[0], s1 = cp[1], s2 = cp[2], s3 = cp[3];
                    int   s4 = cp[4], s5 = cp[5], s6 = cp[6], s7 = cp[7];
                    float q0 = wp[0], q1 = wp[1], q2 = wp[2], q3 = wp[3];
                    float q4 = wp[4], q5 = wp[5], q6 = wp[6], q7 = wp[7];
                    float g0v = XW[(size_t)s0 * 64 + lane];
                    float g1v = XW[(size_t)s1 * 64 + lane];
                    float g2v = XW[(size_t)s2 * 64 + lane];
                    float g3v = XW[(size_t)s3 * 64 + lane];
                    float g4v = XW[(size_t)s4 * 64 + lane];
                    float g5v = XW[(size_t)s5 * 64 + lane];
                    float g6v = XW[(size_t)s6 * 64 + lane];
                    float g7v = XW[(size_t)s7 * 64 + lane];
                    acc = fmaf(q0, g0v, acc); acc = fmaf(q1, g1v, acc);
                    acc = fmaf(q2, g2v, acc); acc = fmaf(q3, g3v, acc);
                    acc = fmaf(q4, g4v, acc); acc = fmaf(q5, g5v, acc);
                    acc = fmaf(q6, g6v, acc); acc = fmaf(q7, g7v, acc);
                }
                for (; j < cnt; ++j) {
                    int s = csr[start + j];
                    acc = fmaf(csrw[start + j], XW[(size_t)s * 64 + lane], acc);
                }
                hv = fmaxf(fmaf(dv, acc, bb), 0.f);
            }
            h[rr] = hv;
        }
        // transpose 4 rows via wave-private LDS (no __syncthreads needed)
        *(float4*)&hb[lane * 4] = make_float4(h[0], h[1], h[2], h[3]);
        float y0 = 0.f, y1 = 0.f, y2 = 0.f, y3 = 0.f;
#pragma unroll
        for (int k = 0; k < 64; ++k) {
            float4 hk = *(const float4*)&hb[k * 4];   // broadcast read
            y0 = fmaf(hk.x, wc[k], y0);
            y1 = fmaf(hk.y, wc[k], y1);
            y2 = fmaf(hk.z, wc[k], y2);
            y3 = fmaf(hk.w, wc[k], y3);
        }
        if (v0 + 0 < N) Y[(size_t)(v0 + 0) * 64 + lane] = y0;
        if (v0 + 1 < N) Y[(size_t)(v0 + 1) * 64 + lane] = y1;
        if (v0 + 2 < N) Y[(size_t)(v0 + 2) * 64 + lane] = y2;
        if (v0 + 3 < N) Y[(size_t)(v0 + 3) * 64 + lane] = y3;
    }
}

// ------- layer2 agg fused with MLP head:  out = relu(relu(agg(Y)+b2)@dW1+db1)@dW2+db2 -------

__global__ void agg_head_kernel(const float* __restrict__ Yin, const int* __restrict__ csr,
                                const float* __restrict__ csrw,
                                const int* __restrict__ rowptr, const int* __restrict__ counts,
                                const float* __restrict__ dinv, const float* __restrict__ b2,
                                const float* __restrict__ dW1, const float* __restrict__ db1,
                                const float* __restrict__ dW2, const float* __restrict__ db2,
                                float* __restrict__ out, int N) {
    __shared__ float tbuf[4][256];      // per-wave transpose scratch
    __shared__ float W2l[64 * 16];      // dW2 staged once
    int tid = threadIdx.x;
    int lane = tid & 63;
    for (int i = tid; i < 1024; i += 256) W2l[i] = dW2[i];
    __syncthreads();
    int wi = __builtin_amdgcn_readfirstlane(tid >> 6);
    float wc[64];                       // dW1 column for this lane
#pragma unroll
    for (int k = 0; k < 64; ++k) wc[k] = dW1[k * 64 + lane];
    float bbl = b2[lane];
    float bb1 = db1[lane];
    int c = lane & 15, rr2 = lane >> 4;
    float ob = db2[c];
    float* tb = &tbuf[wi][0];
    int g0 = blockIdx.x * 4 + wi;
    int ng = gridDim.x * 4;
    int NG = (N + 3) >> 2;
    for (int g = g0; g < NG; g += ng) {
        int v0 = g * 4;
        float h[4];
#pragma unroll
        for (int rr = 0; rr < 4; ++rr) {
            int v = v0 + rr;
            float hv = 0.f;
            if (v < N) {
                int start = rowptr[v];
                int cnt = counts[v];
                float dv = dinv[v];
                float acc = dv * Yin[(size_t)v * 64 + lane];
                int j = 0;
                for (; j + 8 <= cnt; j += 8) {
                    const int*   cp = csr  + start + j;
                    const float* wp = csrw + start + j;
                    int   s0 = cp[0], s1 = cp[1], s2 = cp[2], s3 = cp[3];
                    int   s4 = cp[4], s5 = cp[5], s6 = cp[6], s7 = cp[7];
                    float q0 = wp[0], q1 = wp[1], q2 = wp[2], q3 = wp[3];
                    float q4 = wp[4], q5 = wp[5], q6 = wp[6], q7 = wp[7];
                    float g0v = Yin[(size_t)s0 * 64 + lane];
                    float g1v = Yin[(size_t)s1 * 64 + lane];
                    float g2v = Yin[(size_t)s2 * 64 + lane];
                    float g3v = Yin[(size_t)s3 * 64 + lane];
                    float g4v = Yin[(size_t)s4 * 64 + lane];
                    float g5v = Yin[(size_t)s5 * 64 + lane];
                    float g6v = Yin[(size_t)s6 * 64 + lane];
                    float g7v = Yin[(size_t)s7 * 64 + lane];
                    acc = fmaf(q0, g0v, acc); acc = fmaf(q1, g1v, acc);
                    acc = fmaf(q2, g2v, acc); acc = fmaf(q3, g3v, acc);
                    acc = fmaf(q4, g4v, acc); acc = fmaf(q5, g5v, acc);
                    acc = fmaf(q6, g6v, acc); acc = fmaf(q7, g7v, acc);
                }
                for (; j < cnt; ++j) {
                    int s = csr[start + j];
                    acc = fmaf(csrw[start + j], Yin[(size_t)s * 64 + lane], acc);
                }
                hv = fmaxf(fmaf(dv, acc, bbl), 0.f);   // h2 = relu(agg + b2)
            }
            h[rr] = hv;
        }
        // stage h2 (4 rows) via wave-private LDS
        *(float4*)&tb[lane * 4] = make_float4(h[0], h[1], h[2], h[3]);
        float y0 = bb1, y1 = bb1, y2 = bb1, y3 = bb1;   // d1 = relu(h2@dW1+db1)
#pragma unroll
        for (int k = 0; k < 64; ++k) {
            float4 hk = *(const float4*)&tb[k * 4];
            y0 = fmaf(hk.x, wc[k], y0);
            y1 = fmaf(hk.y, wc[k], y1);
            y2 = fmaf(hk.z, wc[k], y2);
            y3 = fmaf(hk.w, wc[k], y3);
        }
        y0 = fmaxf(y0, 0.f); y1 = fmaxf(y1, 0.f);
        y2 = fmaxf(y2, 0.f); y3 = fmaxf(y3, 0.f);
        // stage d1 (reuse same wave-private buffer; in-wave instruction order is safe)
        *(float4*)&tb[lane * 4] = make_float4(y0, y1, y2, y3);
        float o = 0.f;
#pragma unroll
        for (int k = 0; k < 64; ++k)
            o = fmaf(tb[k * 4 + rr2], W2l[k * 16 + c], o);
        int orow = v0 + rr2;
        if (orow < N) out[(size_t)v0 * 16 + lane] = o + ob;
    }
}

// ---------------- launch ----------------

extern "C" void kernel_launch(void* const* d_in, const int* in_sizes, int n_in,
                              void* d_out, int out_size, void* d_ws, size_t ws_size,
                              hipStream_t stream) {
    const float* x   = (const float*)d_in[0];
    const int*   ei  = (const int*)d_in[1];
    const float* W1  = (const float*)d_in[2];
    const float* b1  = (const float*)d_in[3];
    const float* W2  = (const float*)d_in[4];
    const float* b2  = (const float*)d_in[5];
    const float* dW1 = (const float*)d_in[6];
    const float* db1 = (const float*)d_in[7];
    const float* dW2 = (const float*)d_in[8];
    const float* db2 = (const float*)d_in[9];
    float* out = (float*)d_out;

    int N = in_sizes[0] / 64;
    int E = in_sizes[1] / 2;
    const int* src = ei;
    const int* dst = ei + E;

    size_t off = 0;
    auto alloc = [&](size_t bytes) {
        void* p = (char*)d_ws + off;
        off += (bytes + 511) & ~(size_t)511;
        return p;
    };
    int*   counts = (int*)alloc((size_t)N * 4);
    int*   fillc  = (int*)alloc((size_t)N * 4);
    int*   rowptr = (int*)alloc((size_t)N * 4);
    int*   bsums  = (int*)alloc(512 * 4);
    int*   csr    = (int*)alloc((size_t)E * 4);
    float* csrw   = (float*)alloc((size_t)E * 4);
    float* dinv   = (float*)alloc((size_t)N * 4);
    float* xw     = (float*)alloc((size_t)N * 64 * 4);
    float* yw     = (float*)alloc((size_t)N * 64 * 4);

    hipMemsetAsync(counts, 0, (size_t)N * 4, stream);
    hipMemsetAsync(fillc, 0, (size_t)N * 4, stream);

    int nbN = (N + 255) / 256;      // 391 blocks (fits scan_bsums<=512)
    int nbE = (E + 255) / 256;

    count_kernel<<<nbE, 256, 0, stream>>>(dst, counts, E);
    scan_local<<<nbN, 256, 0, stream>>>(counts, rowptr, bsums, dinv, N);
    scan_bsums<<<1, 512, 0, stream>>>(bsums, nbN);
    scan_add<<<nbN, 256, 0, stream>>>(rowptr, bsums, N);
    fill_kernel<<<nbE, 256, 0, stream>>>(src, dst, rowptr, fillc, dinv, csr, csrw, E);

    gemm64_kernel<<<4096, 256, 0, stream>>>(x, W1, xw, N);
    agg_mm_kernel<<<2048, 256, 0, stream>>>(xw, csr, csrw, rowptr, counts, dinv, b1, W2, yw, N);
    agg_head_kernel<<<2048, 256, 0, stream>>>(yw, csr, csrw, rowptr, counts, dinv, b2,
                                              dW1, db1, dW2, db2, out, N);
}

// Round 4
// 1048.935 us; speedup vs baseline: 1.6628x; 1.0479x over previous
//
#include <hip/hip_runtime.h>

// ---------------- CSR construction ----------------

__global__ void count_kernel(const int* __restrict__ dst, int* __restrict__ counts, int E) {
    int e = blockIdx.x * 256 + threadIdx.x;
    if (e < E) atomicAdd(&counts[dst[e]], 1);
}

__global__ void scan_local(const int* __restrict__ counts, int* __restrict__ rowptr,
                           int* __restrict__ bsums, float* __restrict__ dinv, int N) {
    __shared__ int sm[256];
    int t = threadIdx.x;
    int gid = blockIdx.x * 256 + t;
    int v = (gid < N) ? counts[gid] : 0;
    if (gid < N) dinv[gid] = rsqrtf((float)v + 1.0f);
    int x = v;
    sm[t] = x; __syncthreads();
    for (int off = 1; off < 256; off <<= 1) {
        int y = (t >= off) ? sm[t - off] : 0;
        __syncthreads();
        x += y; sm[t] = x; __syncthreads();
    }
    if (gid < N) rowptr[gid] = x - v;
    if (t == 255) bsums[blockIdx.x] = x;
}

__global__ void scan_bsums(int* bsums, int nb) {
    __shared__ int sm[512];
    int t = threadIdx.x;
    int v = (t < nb) ? bsums[t] : 0;
    int x = v;
    sm[t] = x; __syncthreads();
    for (int off = 1; off < 512; off <<= 1) {
        int y = (t >= off) ? sm[t - off] : 0;
        __syncthreads();
        x += y; sm[t] = x; __syncthreads();
    }
    if (t < nb) bsums[t] = x - v;
}

__global__ void scan_add(int* __restrict__ rowptr, const int* __restrict__ bsums, int N) {
    int gid = blockIdx.x * 256 + threadIdx.x;
    if (gid < N) rowptr[gid] += bsums[blockIdx.x];
}

__global__ void fill_kernel(const int* __restrict__ src, const int* __restrict__ dst,
                            const int* __restrict__ rowptr, int* __restrict__ fillc,
                            const float* __restrict__ dinv,
                            int* __restrict__ csr, float* __restrict__ csrw, int E) {
    int e = blockIdx.x * 256 + threadIdx.x;
    if (e < E) {
        int d = dst[e];
        int s = src[e];
        int pos = rowptr[d] + atomicAdd(&fillc[d], 1);
        csr[pos] = s;
        csrw[pos] = dinv[s];
    }
}

// ---------------- xw = X @ W : lane = out column, W column in VGPRs ----------------
// 128-thread blocks, launch_bounds(128,4) -> 128 VGPR cap: wc[64] fits in registers
// (round-3's 256-thread version allocated 64 VGPRs and spilled wc to scratch -> 1.7GB HBM).

__global__ void __launch_bounds__(128, 4)
gemm64_kernel(const float* __restrict__ X, const float* __restrict__ W,
              float* __restrict__ out, int N) {
    int tid = threadIdx.x;
    int lane = tid & 63;
    int wi = __builtin_amdgcn_readfirstlane(tid >> 6);
    float wc[64];
#pragma unroll
    for (int k = 0; k < 64; ++k) wc[k] = W[k * 64 + lane];
    int r0 = blockIdx.x * 2 + wi;
    int nw = gridDim.x * 2;
    for (int r = r0; r < N; r += nw) {
        const float* xr = X + (size_t)r * 64;   // wave-uniform -> s_load batches
        float a0 = 0.f, a1 = 0.f;
#pragma unroll
        for (int k = 0; k < 64; k += 2) {
            a0 = fmaf(xr[k],     wc[k],     a0);
            a1 = fmaf(xr[k + 1], wc[k + 1], a1);
        }
        out[(size_t)r * 64 + lane] = a0 + a1;
    }
}

// ---------------- layer1 agg fused with @W2:  Y = relu(agg(XW)+b1) @ W2 ----------------

__global__ void __launch_bounds__(128, 4)
agg_mm_kernel(const float* __restrict__ XW, const int* __restrict__ csr,
              const float* __restrict__ csrw,
              const int* __restrict__ rowptr, const int* __restrict__ counts,
              const float* __restrict__ dinv, const float* __restrict__ bias,
              const float* __restrict__ W2, float* __restrict__ Y, int N) {
    __shared__ float hbuf[2][256];      // per-wave transpose scratch
    int tid = threadIdx.x;
    int lane = tid & 63;
    int wi = __builtin_amdgcn_readfirstlane(tid >> 6);
    float wc[64];                       // W2 column for this lane (VGPRs)
#pragma unroll
    for (int k = 0; k < 64; ++k) wc[k] = W2[k * 64 + lane];
    float bb = bias[lane];
    float* hb = &hbuf[wi][0];
    int g0 = blockIdx.x * 2 + wi;
    int ng = gridDim.x * 2;
    int NG = (N + 3) >> 2;
    for (int g = g0; g < NG; g += ng) {
        int v0 = g * 4;
        float h[4];
#pragma unroll
        for (int rr = 0; rr < 4; ++rr) {
            int v = v0 + rr;
            float hv = 0.f;
            if (v < N) {
                int start = rowptr[v];      // uniform -> s_load
                int cnt = counts[v];
                float dv = dinv[v];
                float acc = dv * XW[(size_t)v * 64 + lane];
                int j = 0;
                for (; j + 8 <= cnt; j += 8) {
                    const int*   cp = csr  + start + j;   // uniform -> s_load_dwordx8
                    const float* wp = csrw + start + j;
                    int   s0 = cp[0], s1 = cp[1], s2 = cp[2], s3 = cp[3];
                    int   s4 = cp[4], s5 = cp[5], s6 = cp[6], s7 = cp[7];
                    float q0 = wp[0], q1 = wp[1], q2 = wp[2], q3 = wp[3];
                    float q4 = wp[4], q5 = wp[5], q6 = wp[6], q7 = wp[7];
                    float g0v = XW[(size_t)s0 * 64 + lane];
                    float g1v = XW[(size_t)s1 * 64 + lane];
                    float g2v = XW[(size_t)s2 * 64 + lane];
                    float g3v = XW[(size_t)s3 * 64 + lane];
                    float g4v = XW[(size_t)s4 * 64 + lane];
                    float g5v = XW[(size_t)s5 * 64 + lane];
                    float g6v = XW[(size_t)s6 * 64 + lane];
                    float g7v = XW[(size_t)s7 * 64 + lane];
                    acc = fmaf(q0, g0v, acc); acc = fmaf(q1, g1v, acc);
                    acc = fmaf(q2, g2v, acc); acc = fmaf(q3, g3v, acc);
                    acc = fmaf(q4, g4v, acc); acc = fmaf(q5, g5v, acc);
                    acc = fmaf(q6, g6v, acc); acc = fmaf(q7, g7v, acc);
                }
                for (; j < cnt; ++j) {
                    int s = csr[start + j];
                    acc = fmaf(csrw[start + j], XW[(size_t)s * 64 + lane], acc);
                }
                hv = fmaxf(fmaf(dv, acc, bb), 0.f);
            }
            h[rr] = hv;
        }
        // transpose 4 rows via wave-private LDS (wave-synchronous, no barrier)
        *(float4*)&hb[lane * 4] = make_float4(h[0], h[1], h[2], h[3]);
        float y0 = 0.f, y1 = 0.f, y2 = 0.f, y3 = 0.f;
#pragma unroll
        for (int k = 0; k < 64; ++k) {
            float4 hk = *(const float4*)&hb[k * 4];   // same-address broadcast (free)
            y0 = fmaf(hk.x, wc[k], y0);
            y1 = fmaf(hk.y, wc[k], y1);
            y2 = fmaf(hk.z, wc[k], y2);
            y3 = fmaf(hk.w, wc[k], y3);
        }
        if (v0 + 0 < N) Y[(size_t)(v0 + 0) * 64 + lane] = y0;
        if (v0 + 1 < N) Y[(size_t)(v0 + 1) * 64 + lane] = y1;
        if (v0 + 2 < N) Y[(size_t)(v0 + 2) * 64 + lane] = y2;
        if (v0 + 3 < N) Y[(size_t)(v0 + 3) * 64 + lane] = y3;
    }
}

// ------- layer2 agg fused with MLP head:  out = relu(relu(agg(Y)+b2)@dW1+db1)@dW2+db2 -------

__global__ void __launch_bounds__(128, 4)
agg_head_kernel(const float* __restrict__ Yin, const int* __restrict__ csr,
                const float* __restrict__ csrw,
                const int* __restrict__ rowptr, const int* __restrict__ counts,
                const float* __restrict__ dinv, const float* __restrict__ b2,
                const float* __restrict__ dW1, const float* __restrict__ db1,
                const float* __restrict__ dW2, const float* __restrict__ db2,
                float* __restrict__ out, int N) {
    __shared__ float tbuf[2][256];      // per-wave transpose scratch
    __shared__ float W2l[64 * 16];      // dW2 staged (read as broadcast; avoids VGPR array)
    int tid = threadIdx.x;
    int lane = tid & 63;
    for (int i = tid; i < 1024; i += 128) W2l[i] = dW2[i];
    __syncthreads();
    int wi = __builtin_amdgcn_readfirstlane(tid >> 6);
    float wc[64];                       // dW1 column for this lane (VGPRs)
#pragma unroll
    for (int k = 0; k < 64; ++k) wc[k] = dW1[k * 64 + lane];
    float bbl = b2[lane];
    float bb1 = db1[lane];
    int c = lane & 15, rr2 = lane >> 4;
    float ob = db2[c];
    float* tb = &tbuf[wi][0];
    int g0 = blockIdx.x * 2 + wi;
    int ng = gridDim.x * 2;
    int NG = (N + 3) >> 2;
    for (int g = g0; g < NG; g += ng) {
        int v0 = g * 4;
        float h[4];
#pragma unroll
        for (int rr = 0; rr < 4; ++rr) {
            int v = v0 + rr;
            float hv = 0.f;
            if (v < N) {
                int start = rowptr[v];
                int cnt = counts[v];
                float dv = dinv[v];
                float acc = dv * Yin[(size_t)v * 64 + lane];
                int j = 0;
                for (; j + 8 <= cnt; j += 8) {
                    const int*   cp = csr  + start + j;
                    const float* wp = csrw + start + j;
                    int   s0 = cp[0], s1 = cp[1], s2 = cp[2], s3 = cp[3];
                    int   s4 = cp[4], s5 = cp[5], s6 = cp[6], s7 = cp[7];
                    float q0 = wp[0], q1 = wp[1], q2 = wp[2], q3 = wp[3];
                    float q4 = wp[4], q5 = wp[5], q6 = wp[6], q7 = wp[7];
                    float g0v = Yin[(size_t)s0 * 64 + lane];
                    float g1v = Yin[(size_t)s1 * 64 + lane];
                    float g2v = Yin[(size_t)s2 * 64 + lane];
                    float g3v = Yin[(size_t)s3 * 64 + lane];
                    float g4v = Yin[(size_t)s4 * 64 + lane];
                    float g5v = Yin[(size_t)s5 * 64 + lane];
                    float g6v = Yin[(size_t)s6 * 64 + lane];
                    float g7v = Yin[(size_t)s7 * 64 + lane];
                    acc = fmaf(q0, g0v, acc); acc = fmaf(q1, g1v, acc);
                    acc = fmaf(q2, g2v, acc); acc = fmaf(q3, g3v, acc);
                    acc = fmaf(q4, g4v, acc); acc = fmaf(q5, g5v, acc);
                    acc = fmaf(q6, g6v, acc); acc = fmaf(q7, g7v, acc);
                }
                for (; j < cnt; ++j) {
                    int s = csr[start + j];
                    acc = fmaf(csrw[start + j], Yin[(size_t)s * 64 + lane], acc);
                }
                hv = fmaxf(fmaf(dv, acc, bbl), 0.f);   // h2 = relu(agg + b2)
            }
            h[rr] = hv;
        }
        // stage h2 (4 rows), compute d1 = relu(h2@dW1+db1)
        *(float4*)&tb[lane * 4] = make_float4(h[0], h[1], h[2], h[3]);
        float y0 = bb1, y1 = bb1, y2 = bb1, y3 = bb1;
#pragma unroll
        for (int k = 0; k < 64; ++k) {
            float4 hk = *(const float4*)&tb[k * 4];
            y0 = fmaf(hk.x, wc[k], y0);
            y1 = fmaf(hk.y, wc[k], y1);
            y2 = fmaf(hk.z, wc[k], y2);
            y3 = fmaf(hk.w, wc[k], y3);
        }
        y0 = fmaxf(y0, 0.f); y1 = fmaxf(y1, 0.f);
        y2 = fmaxf(y2, 0.f); y3 = fmaxf(y3, 0.f);
        // stage d1 (reuse wave-private buffer; in-wave DS ordering is safe)
        *(float4*)&tb[lane * 4] = make_float4(y0, y1, y2, y3);
        float o = 0.f;
#pragma unroll
        for (int k = 0; k < 64; ++k)
            o = fmaf(tb[k * 4 + rr2], W2l[k * 16 + c], o);   // both broadcast reads
        int orow = v0 + rr2;
        if (orow < N) out[(size_t)v0 * 16 + lane] = o + ob;
    }
}

// ---------------- launch ----------------

extern "C" void kernel_launch(void* const* d_in, const int* in_sizes, int n_in,
                              void* d_out, int out_size, void* d_ws, size_t ws_size,
                              hipStream_t stream) {
    const float* x   = (const float*)d_in[0];
    const int*   ei  = (const int*)d_in[1];
    const float* W1  = (const float*)d_in[2];
    const float* b1  = (const float*)d_in[3];
    const float* W2  = (const float*)d_in[4];
    const float* b2  = (const float*)d_in[5];
    const float* dW1 = (const float*)d_in[6];
    const float* db1 = (const float*)d_in[7];
    const float* dW2 = (const float*)d_in[8];
    const float* db2 = (const float*)d_in[9];
    float* out = (float*)d_out;

    int N = in_sizes[0] / 64;
    int E = in_sizes[1] / 2;
    const int* src = ei;
    const int* dst = ei + E;

    size_t off = 0;
    auto alloc = [&](size_t bytes) {
        void* p = (char*)d_ws + off;
        off += (bytes + 511) & ~(size_t)511;
        return p;
    };
    int*   counts = (int*)alloc((size_t)N * 4);
    int*   fillc  = (int*)alloc((size_t)N * 4);
    int*   rowptr = (int*)alloc((size_t)N * 4);
    int*   bsums  = (int*)alloc(512 * 4);
    int*   csr    = (int*)alloc((size_t)E * 4);
    float* csrw   = (float*)alloc((size_t)E * 4);
    float* dinv   = (float*)alloc((size_t)N * 4);
    float* xw     = (float*)alloc((size_t)N * 64 * 4);
    float* yw     = (float*)alloc((size_t)N * 64 * 4);

    hipMemsetAsync(counts, 0, (size_t)N * 4, stream);
    hipMemsetAsync(fillc, 0, (size_t)N * 4, stream);

    int nbN = (N + 255) / 256;
    int nbE = (E + 255) / 256;

    count_kernel<<<nbE, 256, 0, stream>>>(dst, counts, E);
    scan_local<<<nbN, 256, 0, stream>>>(counts, rowptr, bsums, dinv, N);
    scan_bsums<<<1, 512, 0, stream>>>(bsums, nbN);
    scan_add<<<nbN, 256, 0, stream>>>(rowptr, bsums, N);
    fill_kernel<<<nbE, 256, 0, stream>>>(src, dst, rowptr, fillc, dinv, csr, csrw, E);

    gemm64_kernel<<<4096, 128, 0, stream>>>(x, W1, xw, N);
    agg_mm_kernel<<<4096, 128, 0, stream>>>(xw, csr, csrw, rowptr, counts, dinv, b1, W2, yw, N);
    agg_head_kernel<<<4096, 128, 0, stream>>>(yw, csr, csrw, rowptr, counts, dinv, b2,
                                              dW1, db1, dW2, db2, out, N);
}